// Round 1
// baseline (78.020 us; speedup 1.0000x reference)
//
#include <hip/hip_runtime.h>
#include <hip/hip_bf16.h>

typedef __bf16 bf16x8 __attribute__((ext_vector_type(8)));
typedef float  f32x4  __attribute__((ext_vector_type(4)));

#define CIN   64
#define COUT  128
#define HH    128
#define WW    128
#define BB    8
#define CKPAD 72   // padded c-dim (bf16) -> row stride 144B (16B-aligned)

// ---------------- prep: pack weights into MFMA-B fragment order (bf16) ----------
// Bprep[((n*18 + s)*64 + lane)*8 + j] = W2[o][ck],
//   o = n*16 + (lane&15); c = (s&1)*32 + ((lane>>4)&3)*8 + j; k = s>>1; ck = c*9+k
//   W2[o][ck] = wflat[o*576 + ck]   (torch .view semantics: flat reindex)
__global__ void prep_weights(const float* __restrict__ wflat, __bf16* __restrict__ bp) {
    int idx = blockIdx.x * 256 + threadIdx.x;
    if (idx >= 8 * 18 * 64 * 8) return;
    int j = idx & 7;
    int l = (idx >> 3) & 63;
    int s = (idx >> 9) % 18;
    int n = idx / (18 * 512);
    int o = n * 16 + (l & 15);
    int c = ((s & 1) << 5) + ((l >> 4) << 3) + j;
    int k = s >> 1;
    bp[idx] = (__bf16)wflat[o * 576 + c * 9 + k];
}

// ---------------- main: one block per (b, y) output row -------------------------
__global__ __launch_bounds__(256, 2) void depthcnn_main(
    const float* __restrict__ inp, const float* __restrict__ gbuf,
    const float* __restrict__ bias, const __bf16* __restrict__ bprep,
    float* __restrict__ out)
{
    __shared__ __align__(16) __bf16 sIn[3][130][CKPAD];  // 56160 B
    __shared__ float sWf[9][WW];                          // 4608 B

    const int b   = blockIdx.x >> 7;
    const int y   = blockIdx.x & 127;
    const int tid = threadIdx.x;

    // ---- stage input halo: 3 rows x 130 cols x 64 ch, transposed to c-innermost bf16
    {
        const float* base = inp + (long)b * CIN * (HH * WW);
        for (int e = tid; e < 3 * 64 * 32; e += 256) {
            int dy  = e / (64 * 32);
            int rem = e - dy * (64 * 32);
            int c   = rem >> 5;
            int xq  = rem & 31;
            int ys  = y + dy - 1;
            float4 v = make_float4(0.f, 0.f, 0.f, 0.f);
            if ((unsigned)ys < 128u)
                v = *(const float4*)(base + (c * HH + ys) * WW + (xq << 2));
            __bf16* w = &sIn[dy][xq * 4 + 1][c];
            w[0 * CKPAD] = (__bf16)v.x;
            w[1 * CKPAD] = (__bf16)v.y;
            w[2 * CKPAD] = (__bf16)v.z;
            w[3 * CKPAD] = (__bf16)v.w;
        }
        for (int e = tid; e < 3 * 64 * 2; e += 256) {  // halo edge columns (x=-1, x=128)
            int dy  = e >> 7;
            int rem = e & 127;
            int c   = rem >> 1;
            int xx  = (rem & 1) ? 129 : 0;
            sIn[dy][xx][c] = (__bf16)0.f;
        }
    }
    // ---- bilateral weights wf[9][x] for this row (OOB depth = 0 enters denominator)
    if (tid < WW) {
        const float* g = gbuf + ((long)b * 2 + 1) * (HH * WW);
        const int x = tid;
        float dc = 2.f * (g[y * WW + x] - 0.5f);
        float e[9];
        float ssum = 0.f;
        #pragma unroll
        for (int k = 0; k < 9; ++k) {
            int yy = y + (k / 3) - 1;
            int xx = x + (k % 3) - 1;
            float dn = 0.f;
            if ((unsigned)yy < 128u && (unsigned)xx < 128u)
                dn = 2.f * (g[yy * WW + xx] - 0.5f);
            float df = dn - dc;
            float ek = __expf(-df * df);
            e[k] = ek;
            ssum += ek;
        }
        float sc = 9.f / ssum;
        #pragma unroll
        for (int k = 0; k < 9; ++k) sWf[k][x] = e[k] * sc;
    }
    __syncthreads();

    const int wave = tid >> 6;
    const int lane = tid & 63;
    const int m16  = lane & 15;   // A row / B col within 16
    const int g4   = lane >> 4;   // k-group
    const int x0   = wave << 5;   // 32 pixels per wave

    f32x4 acc[2][8];
    #pragma unroll
    for (int mi = 0; mi < 2; ++mi)
        #pragma unroll
        for (int n = 0; n < 8; ++n)
            acc[mi][n] = (f32x4){0.f, 0.f, 0.f, 0.f};

    const bf16x8* __restrict__ bp = (const bf16x8*)bprep;

    #pragma unroll
    for (int s = 0; s < 18; ++s) {
        const int k  = s >> 1;
        const int dy = k / 3;
        const int dx = k - 3 * dy;
        const int c0 = ((s & 1) << 5) + (g4 << 3);
        bf16x8 afr[2];
        #pragma unroll
        for (int mi = 0; mi < 2; ++mi) {
            const int xl = x0 + mi * 16 + m16;
            bf16x8 iv = *(const bf16x8*)&sIn[dy][xl + dx][c0];  // 16B aligned
            float wfv = sWf[k][xl];
            bf16x8 a;
            #pragma unroll
            for (int j = 0; j < 8; ++j) a[j] = (__bf16)((float)iv[j] * wfv);
            afr[mi] = a;
        }
        #pragma unroll
        for (int n = 0; n < 8; ++n) {
            bf16x8 bfr = bp[(n * 18 + s) * 64 + lane];
            acc[0][n] = __builtin_amdgcn_mfma_f32_16x16x32_bf16(afr[0], bfr, acc[0][n], 0, 0, 0);
            acc[1][n] = __builtin_amdgcn_mfma_f32_16x16x32_bf16(afr[1], bfr, acc[1][n], 0, 0, 0);
        }
    }

    // ---- epilogue: D[row=pixel][col=o] ; row = (l>>4)*4 + r, col = l&15
    float* ob = out + ((long)b * COUT * HH + y) * WW;
    #pragma unroll
    for (int n = 0; n < 8; ++n) {
        int o = n * 16 + m16;
        float bv = bias[o];
        #pragma unroll
        for (int mi = 0; mi < 2; ++mi) {
            #pragma unroll
            for (int r = 0; r < 4; ++r) {
                int px = x0 + mi * 16 + g4 * 4 + r;
                ob[(long)o * (HH * WW) + px] = acc[mi][n][r] + bv;
            }
        }
    }
}

extern "C" void kernel_launch(void* const* d_in, const int* in_sizes, int n_in,
                              void* d_out, int out_size, void* d_ws, size_t ws_size,
                              hipStream_t stream) {
    const float* inp  = (const float*)d_in[0];
    const float* gbuf = (const float*)d_in[1];
    const float* wts  = (const float*)d_in[2];
    const float* bias = (const float*)d_in[3];
    __bf16* bp = (__bf16*)d_ws;  // 147456 B

    hipLaunchKernelGGL(prep_weights, dim3(288), dim3(256), 0, stream, wts, bp);
    hipLaunchKernelGGL(depthcnn_main, dim3(BB * HH), dim3(256), 0, stream,
                       inp, gbuf, bias, bp, (float*)d_out);
}